// Round 3
// baseline (1115.366 us; speedup 1.0000x reference)
//
#include <hip/hip_runtime.h>
#include <math.h>

#define NVERT 6890
#define NBATCH 1024
#define V3 20670         // NVERT*3
#define NPAD 20736       // 162*128
#define KPAD 224         // 207 pose + 10 shape + 7 zero
#define NSLICE 8
#define SLICE_V 864

// workspace layout (float offsets)
#define WS_SJP 0                 // NSLICE*792
#define WS_SJF 6336              // 792
#define WS_A   8192              // 1024*384 fp32 A'
#define WS_PFT 401408            // fp16 PF-ext [1024][224]  (114688 floats)
#define WS_PDT 516096            // fp16 PD-ext [20736][224] (2322432 floats)

typedef _Float16 half8 __attribute__((ext_vector_type(8)));
typedef float f32x4 __attribute__((ext_vector_type(4)));

// ---------------------------------------------------------------------------
// K0: partial reductions of SJ/JT over vertex slices. grid (24, 8) x 256
// ---------------------------------------------------------------------------
__global__ __launch_bounds__(256) void k0_joint_reduce(
    const float* __restrict__ v_template,
    const float* __restrict__ shapedirs,
    const float* __restrict__ J_regressor,
    float* __restrict__ ws)
{
    int j = blockIdx.x;
    int s = blockIdx.y;
    int t = threadIdx.x;
    int lane = t & 63, wid = t >> 6;
    int v0 = s * SLICE_V;
    int v1 = v0 + SLICE_V; if (v1 > NVERT) v1 = NVERT;

    float acc[33];
#pragma unroll
    for (int i = 0; i < 33; ++i) acc[i] = 0.f;

    for (int v = v0 + t; v < v1; v += 256) {
        float jr = J_regressor[v * 24 + j];
        const float* vp = v_template + v * 3;
        acc[30] = fmaf(vp[0], jr, acc[30]);
        acc[31] = fmaf(vp[1], jr, acc[31]);
        acc[32] = fmaf(vp[2], jr, acc[32]);
#pragma unroll
        for (int k = 0; k < 10; ++k) {
            const float* p = shapedirs + k * V3 + v * 3;
            acc[k * 3 + 0] = fmaf(p[0], jr, acc[k * 3 + 0]);
            acc[k * 3 + 1] = fmaf(p[1], jr, acc[k * 3 + 1]);
            acc[k * 3 + 2] = fmaf(p[2], jr, acc[k * 3 + 2]);
        }
    }

#pragma unroll
    for (int i = 0; i < 33; ++i) {
#pragma unroll
        for (int o = 32; o > 0; o >>= 1)
            acc[i] += __shfl_xor(acc[i], o, 64);
    }

    __shared__ float part[4][33];
    if (lane == 0) {
#pragma unroll
        for (int i = 0; i < 33; ++i) part[wid][i] = acc[i];
    }
    __syncthreads();
    if (t < 33) {
        float r = part[0][t] + part[1][t] + part[2][t] + part[3][t];
        int k = t / 3, c = t % 3;
        int off = (k < 10) ? (WS_SJP + s * 792 + k * 72 + j * 3 + c)
                           : (WS_SJP + s * 792 + 720 + j * 3 + c);
        ws[off] = r;
    }
}

__global__ __launch_bounds__(256) void k0b_sum(float* __restrict__ ws)
{
    int i = blockIdx.x * 256 + threadIdx.x;
    if (i < 792) {
        float r = 0.f;
#pragma unroll
        for (int s = 0; s < NSLICE; ++s) r += ws[WS_SJP + s * 792 + i];
        ws[WS_SJF + i] = r;
    }
}

// ---------------------------------------------------------------------------
// C0: build PDt fp16 [NPAD][KPAD] = transpose of [posedirs ; shapedirs ; 0]
// grid 324 x 256: lane = k (<224), n-loop of 64 per block.
// ---------------------------------------------------------------------------
__global__ __launch_bounds__(256) void c0_convert(
    const float* __restrict__ posedirs,
    const float* __restrict__ shapedirs,
    float* __restrict__ ws)
{
    _Float16* pdt = (_Float16*)(ws + WS_PDT);
    int k = threadIdx.x;
    int n0 = blockIdx.x * 64;
    if (k >= KPAD) return;

    const float* src = nullptr;
    if (k < 207)      src = posedirs + (size_t)k * V3;
    else if (k < 217) src = shapedirs + (size_t)(k - 207) * V3;

    for (int i = 0; i < 64; ++i) {
        int n = n0 + i;
        float val = (src && n < V3) ? src[n] : 0.f;
        pdt[(size_t)n * KPAD + k] = (_Float16)val;
    }
}

// ---------------------------------------------------------------------------
// K1: Rodrigues + J + kinematic chain -> A' (fp32) and PF-ext (fp16).
// grid 256 x 256 (wave = 1 batch, wave-synchronous: no barriers needed)
// ---------------------------------------------------------------------------
__global__ __launch_bounds__(256) void k1_pose(
    const float* __restrict__ theta,
    const float* __restrict__ beta,
    float* __restrict__ ws)
{
    int t = threadIdx.x;
    int lane = t & 63, wid = t >> 6;
    int b = blockIdx.x * 4 + wid;

    __shared__ float Rs[4][24][9];
    __shared__ float Jl[4][24][3];
    __shared__ float res[4][24][16];
    __shared__ float Ai[4][16];

    if (lane < 24) {
        float tx = theta[b * 72 + lane * 3 + 0];
        float ty = theta[b * 72 + lane * 3 + 1];
        float tz = theta[b * 72 + lane * 3 + 2];
        float ax = tx + 1e-8f, ay = ty + 1e-8f, az = tz + 1e-8f;
        float ang = sqrtf(ax * ax + ay * ay + az * az);
        float h = 0.5f * ang;
        float cw = cosf(h), sw = sinf(h);
        float qw = cw;
        float qx = sw * (tx / ang);
        float qy = sw * (ty / ang);
        float qz = sw * (tz / ang);
        float qn = sqrtf(qw * qw + qx * qx + qy * qy + qz * qz);
        qw /= qn; qx /= qn; qy /= qn; qz /= qn;
        float w2 = qw * qw, x2 = qx * qx, y2 = qy * qy, z2 = qz * qz;
        float wx = qw * qx, wy = qw * qy, wz = qw * qz;
        float xy = qx * qy, xz = qx * qz, yz = qy * qz;
        Rs[wid][lane][0] = w2 + x2 - y2 - z2;
        Rs[wid][lane][1] = 2.f * xy - 2.f * wz;
        Rs[wid][lane][2] = 2.f * wy + 2.f * xz;
        Rs[wid][lane][3] = 2.f * wz + 2.f * xy;
        Rs[wid][lane][4] = w2 - x2 + y2 - z2;
        Rs[wid][lane][5] = 2.f * yz - 2.f * wx;
        Rs[wid][lane][6] = 2.f * xz - 2.f * wy;
        Rs[wid][lane][7] = 2.f * wx + 2.f * yz;
        Rs[wid][lane][8] = w2 - x2 - y2 + z2;
    }

    // J = JT + beta @ SJ
    for (int i = lane; i < 72; i += 64) {
        float sacc = ws[WS_SJF + 720 + i];
#pragma unroll
        for (int k = 0; k < 10; ++k)
            sacc = fmaf(beta[b * 10 + k], ws[WS_SJF + k * 72 + i], sacc);
        Jl[wid][i / 3][i % 3] = sacc;
    }

    // PF-ext fp16: [pf(207) | beta(10) | 0]
    {
        _Float16* pft = (_Float16*)(ws + WS_PFT);
        for (int i = lane; i < KPAD; i += 64) {
            float val;
            if (i < 207) {
                int jj = 1 + i / 9, e = i % 9;
                float sub = (e == 0 || e == 4 || e == 8) ? 1.f : 0.f;
                val = Rs[wid][jj][e] - sub;
            } else if (i < 217) {
                val = beta[b * 10 + (i - 207)];
            } else val = 0.f;
            pft[(size_t)b * KPAD + i] = (_Float16)val;
        }
    }

    if (lane < 16) {
        int r = lane >> 2, c = lane & 3;
        res[wid][0][lane] = (r < 3) ? (c < 3 ? Rs[wid][0][r * 3 + c] : Jl[wid][0][r])
                                    : (c == 3 ? 1.f : 0.f);
    }

    const int PAR[24] = {-1,0,0,0,1,2,3,4,5,6,7,8,9,9,9,12,13,14,16,17,18,19,20,21};
#pragma unroll
    for (int i = 1; i < 24; ++i) {
        int p = PAR[i];
        if (lane < 16) {
            int r = lane >> 2, c = lane & 3;
            Ai[wid][lane] = (r < 3) ? (c < 3 ? Rs[wid][i][r * 3 + c]
                                             : (Jl[wid][i][r] - Jl[wid][p][r]))
                                    : (c == 3 ? 1.f : 0.f);
            float sacc = 0.f;
#pragma unroll
            for (int k = 0; k < 4; ++k)
                sacc = fmaf(res[wid][p][r * 4 + k], Ai[wid][k * 4 + c], sacc);
            res[wid][i][lane] = sacc;
        }
    }

    for (int i = lane; i < 384; i += 64) {
        int jj = i >> 4, rc = i & 15, r = rc >> 2, cc = rc & 3;
        float val = res[wid][jj][rc];
        if (cc == 3 && r < 3) {
            val -= res[wid][jj][r * 4 + 0] * Jl[wid][jj][0]
                 + res[wid][jj][r * 4 + 1] * Jl[wid][jj][1]
                 + res[wid][jj][r * 4 + 2] * Jl[wid][jj][2];
        }
        ws[WS_A + b * 384 + i] = val;
    }
}

// ---------------------------------------------------------------------------
// K2: fp16 MFMA GEMM: C[1024][20670] = PF-ext @ PD-ext^T  -> written to d_out
// BM=128, BN=128, 4 waves (each: full 128 M x 32 N), K=224 (7 steps).
// grid (162 n-tiles, 8 m-tiles) x 256
// ---------------------------------------------------------------------------
__global__ __launch_bounds__(256, 2) void k2_gemm(
    const float* __restrict__ ws,
    float* __restrict__ out)
{
    const _Float16* Ap = (const _Float16*)(ws + WS_PFT);
    const _Float16* Bp = (const _Float16*)(ws + WS_PDT);
    int lane = threadIdx.x & 63, wv = threadIdx.x >> 6;
    int rowA = lane & 15;     // A-row-in-tile / B-col-in-tile / C-col
    int kg   = lane >> 4;     // k-group (8 elems) / C row-group
    int m0 = blockIdx.y * 128;
    int n0 = blockIdx.x * 128 + wv * 32;

    f32x4 acc[8][2];
#pragma unroll
    for (int mi = 0; mi < 8; ++mi)
#pragma unroll
        for (int ni = 0; ni < 2; ++ni)
            acc[mi][ni] = (f32x4){0.f, 0.f, 0.f, 0.f};

#pragma unroll 2
    for (int ks = 0; ks < 7; ++ks) {
        int koff = ks * 32 + kg * 8;
        half8 bfrag[2];
#pragma unroll
        for (int ni = 0; ni < 2; ++ni)
            bfrag[ni] = *(const half8*)(Bp + (size_t)(n0 + ni * 16 + rowA) * KPAD + koff);
        half8 afrag[8];
#pragma unroll
        for (int mi = 0; mi < 8; ++mi)
            afrag[mi] = *(const half8*)(Ap + (size_t)(m0 + mi * 16 + rowA) * KPAD + koff);
#pragma unroll
        for (int mi = 0; mi < 8; ++mi)
#pragma unroll
            for (int ni = 0; ni < 2; ++ni)
                acc[mi][ni] = __builtin_amdgcn_mfma_f32_16x16x32_f16(
                    afrag[mi], bfrag[ni], acc[mi][ni], 0, 0, 0);
    }

#pragma unroll
    for (int mi = 0; mi < 8; ++mi)
#pragma unroll
        for (int ni = 0; ni < 2; ++ni) {
            int cc = n0 + ni * 16 + rowA;
            if (cc < V3) {
                int rbase = m0 + mi * 16 + kg * 4;
#pragma unroll
                for (int r = 0; r < 4; ++r)
                    out[(size_t)(rbase + r) * V3 + cc] = acc[mi][ni][r];
            }
        }
}

// ---------------------------------------------------------------------------
// K3: in-place skinning on d_out. Block: 16 batches (LDS A') x 256 vertices.
// lane = (b = lane&15, vgroup = lane>>4), 4 vertices per lane, 4 passes.
// grid (64 bgroups, 27 vchunks) x 256
// ---------------------------------------------------------------------------
__global__ __launch_bounds__(256, 2) void k3_skin(
    const float* __restrict__ v_template,
    const float* __restrict__ weights,
    const float* __restrict__ ws,
    float* out)
{
    __shared__ float A_s[16][388];   // padded: lane-b -> distinct bank pairs
    int t = threadIdx.x;
    int bg = blockIdx.x, chunk = blockIdx.y;

    for (int i = t; i < 16 * 384; i += 256) {
        int bi = i / 384, e = i - bi * 384;
        A_s[bi][e] = ws[WS_A + (bg * 16 + bi) * 384 + e];
    }
    __syncthreads();

    int lane = t & 63, wv = t >> 6;
    int bl = lane & 15, vg = lane >> 4;
    int b = bg * 16 + bl;
    float* ob = out + (size_t)b * V3;

    for (int p = 0; p < 4; ++p) {
        int v0 = chunk * 256 + p * 64 + wv * 16 + vg * 4;

        // per-vertex loads (scalar, clamped)
        float px[4], py[4], pz[4];
        float wsc[4][24];
#pragma unroll
        for (int vi = 0; vi < 4; ++vi) {
            int vcl = v0 + vi; if (vcl > NVERT - 1) vcl = NVERT - 1;
            const float* pp = ob + vcl * 3;
            const float* vt = v_template + vcl * 3;
            px[vi] = pp[0] + vt[0];
            py[vi] = pp[1] + vt[1];
            pz[vi] = pp[2] + vt[2];
            const float4* wr = (const float4*)(weights + vcl * 24);
#pragma unroll
            for (int q = 0; q < 6; ++q) {
                float4 wq = wr[q];
                wsc[vi][q * 4 + 0] = wq.x;
                wsc[vi][q * 4 + 1] = wq.y;
                wsc[vi][q * 4 + 2] = wq.z;
                wsc[vi][q * 4 + 3] = wq.w;
            }
        }

        float o0[4] = {0.f,0.f,0.f,0.f}, o1[4] = {0.f,0.f,0.f,0.f}, o2[4] = {0.f,0.f,0.f,0.f};
        const float4* ar = (const float4*)(&A_s[bl][0]);
#pragma unroll
        for (int j = 0; j < 24; ++j) {
            float4 r0 = ar[j * 4 + 0];
            float4 r1 = ar[j * 4 + 1];
            float4 r2 = ar[j * 4 + 2];
#pragma unroll
            for (int vi = 0; vi < 4; ++vi) {
                float x = px[vi], y = py[vi], z = pz[vi];
                float y0 = fmaf(r0.x, x, fmaf(r0.y, y, fmaf(r0.z, z, r0.w)));
                float y1 = fmaf(r1.x, x, fmaf(r1.y, y, fmaf(r1.z, z, r1.w)));
                float y2 = fmaf(r2.x, x, fmaf(r2.y, y, fmaf(r2.z, z, r2.w)));
                float wj = wsc[vi][j];
                o0[vi] = fmaf(wj, y0, o0[vi]);
                o1[vi] = fmaf(wj, y1, o1[vi]);
                o2[vi] = fmaf(wj, y2, o2[vi]);
            }
        }

#pragma unroll
        for (int vi = 0; vi < 4; ++vi) {
            int vlog = v0 + vi;
            if (vlog < NVERT) {
                float* po = ob + vlog * 3;
                po[0] = o0[vi]; po[1] = o1[vi]; po[2] = o2[vi];
            }
        }
    }
}

extern "C" void kernel_launch(void* const* d_in, const int* in_sizes, int n_in,
                              void* d_out, int out_size, void* d_ws, size_t ws_size,
                              hipStream_t stream) {
    const float* theta       = (const float*)d_in[0];
    const float* beta        = (const float*)d_in[1];
    const float* v_template  = (const float*)d_in[2];
    const float* shapedirs   = (const float*)d_in[3];
    const float* posedirs    = (const float*)d_in[4];
    const float* J_regressor = (const float*)d_in[5];
    const float* weights     = (const float*)d_in[6];
    float* out = (float*)d_out;
    float* ws  = (float*)d_ws;

    hipLaunchKernelGGL(k0_joint_reduce, dim3(24, NSLICE), dim3(256), 0, stream,
                       v_template, shapedirs, J_regressor, ws);
    hipLaunchKernelGGL(k0b_sum, dim3(4), dim3(256), 0, stream, ws);
    hipLaunchKernelGGL(c0_convert, dim3(324), dim3(256), 0, stream,
                       posedirs, shapedirs, ws);
    hipLaunchKernelGGL(k1_pose, dim3(NBATCH / 4), dim3(256), 0, stream,
                       theta, beta, ws);
    hipLaunchKernelGGL(k2_gemm, dim3(NPAD / 128, NBATCH / 128), dim3(256), 0, stream,
                       ws, out);
    hipLaunchKernelGGL(k3_skin, dim3(64, 27), dim3(256), 0, stream,
                       v_template, weights, ws, out);
}